// Round 2
// 484.506 us; speedup vs baseline: 1.1210x; 1.1210x over previous
//
#include <hip/hip_runtime.h>
#include <stdint.h>

#define IN_F   4096
#define OUT_F  4096
#define M_TOT  8192   // 4 * 2048
#define BK     32
#define NT     (IN_F / BK)   // 128 K-tiles
#define BUF_B  32768         // bytes per LDS buffer: A 16K + B 16K
#define NBUF   4             // ring depth (128 KiB total, STATIC LDS)

typedef __bf16 bf16x8 __attribute__((ext_vector_type(8)));
typedef float  floatx4 __attribute__((ext_vector_type(4)));

// counted vmcnt wait: keeps newest N vmem ops in flight (T4)
#define WAITVM(N) asm volatile("s_waitcnt vmcnt(" #N ")" ::: "memory")
// raw barrier WITHOUT the compiler's implicit vmcnt(0) drain; fenced at IR
// level (memory clobber) and MIR level (sched_barrier) so memory ops cannot
// cross it (rule #18-adjacent hazard).
#define FENCE_BARRIER() do {                          \
    asm volatile("" ::: "memory");                    \
    __builtin_amdgcn_s_barrier();                     \
    asm volatile("" ::: "memory");                    \
    __builtin_amdgcn_sched_barrier(0);                \
} while (0)

__device__ __forceinline__ unsigned short f2bf_bits(float f) {
    union { float f; uint32_t u; } v; v.f = f;
    uint32_t r = v.u + 0x7FFF + ((v.u >> 16) & 1);   // RNE
    return (unsigned short)(r >> 16);
}

__device__ __forceinline__ void gl_lds16(const void* g, void* l) {
    __builtin_amdgcn_global_load_lds(
        (const __attribute__((address_space(1))) void*)g,
        (__attribute__((address_space(3))) void*)l, 16, 0, 0);
}

// ---- x: fp32 -> bf16, 8 elements/thread (16B stores) ----
__global__ void cvt_x_kernel(const float* __restrict__ x, ushort* __restrict__ xb) {
    int i = blockIdx.x * blockDim.x + threadIdx.x;
    const float4* xp = reinterpret_cast<const float4*>(x);
    float4 a = xp[2 * i], b = xp[2 * i + 1];
    uint4 o;
    o.x = (uint32_t)f2bf_bits(a.x) | ((uint32_t)f2bf_bits(a.y) << 16);
    o.y = (uint32_t)f2bf_bits(a.z) | ((uint32_t)f2bf_bits(a.w) << 16);
    o.z = (uint32_t)f2bf_bits(b.x) | ((uint32_t)f2bf_bits(b.y) << 16);
    o.w = (uint32_t)f2bf_bits(b.z) | ((uint32_t)f2bf_bits(b.w) << 16);
    reinterpret_cast<uint4*>(xb)[i] = o;
}

// ---- W: packed int4 -> bf16, 4 packed (8 weights)/thread; all 8 in one group ----
__global__ void dequant_kernel(const int* __restrict__ packed,
                               const float* __restrict__ scales,
                               const float* __restrict__ offsets,
                               ushort* __restrict__ wb) {
    int i = blockIdx.x * blockDim.x + threadIdx.x;   // chunk of 4 packed ints
    int4 p = reinterpret_cast<const int4*>(packed)[i];
    int g = i >> 4;                                  // (8*i)/128
    float s = scales[g], off = offsets[g];
    uint4 ov;
    {
        int pv = p.x;
        unsigned w0 = f2bf_bits((float)(pv & 0xF) * s + off);
        unsigned w1 = f2bf_bits((float)((pv >> 4) & 0xF) * s + off);
        ov.x = w0 | (w1 << 16);
    }
    {
        int pv = p.y;
        unsigned w0 = f2bf_bits((float)(pv & 0xF) * s + off);
        unsigned w1 = f2bf_bits((float)((pv >> 4) & 0xF) * s + off);
        ov.y = w0 | (w1 << 16);
    }
    {
        int pv = p.z;
        unsigned w0 = f2bf_bits((float)(pv & 0xF) * s + off);
        unsigned w1 = f2bf_bits((float)((pv >> 4) & 0xF) * s + off);
        ov.z = w0 | (w1 << 16);
    }
    {
        int pv = p.w;
        unsigned w0 = f2bf_bits((float)(pv & 0xF) * s + off);
        unsigned w1 = f2bf_bits((float)((pv >> 4) & 0xF) * s + off);
        ov.w = w0 | (w1 << 16);
    }
    reinterpret_cast<uint4*>(wb)[i] = ov;
}

// ---- GEMM: C[M_TOT][OUT_F] = A[M_TOT][IN_F] * B[OUT_F][IN_F]^T + bias ----
// 256x256 tile, BK=32, 512 threads (2x4 waves, each 128x64 via 8x4 MFMA 16x16x32).
// 4-buffer STATIC-LDS ring (128 KiB), stage 3 tiles ahead, vmcnt(8) leaves 2
// K-tiles of loads in flight across each raw s_barrier (T4). LDS swizzle: data
// for column-byte cb of row r stored at cb ^ (((r>>1)&3)<<4); achieved by
// inverse-swizzling the per-lane GLOBAL source address (LDS dest stays linear,
// required by global_load_lds) and swizzling the ds_read address (rule #21).
__launch_bounds__(512, 2)
__global__ void gemm_kernel(const ushort* __restrict__ A,   // bf16 [M_TOT][IN_F]
                            const ushort* __restrict__ B,   // bf16 [OUT_F][IN_F]
                            const float* __restrict__ bias,
                            float* __restrict__ C) {
    __shared__ __align__(16) char smem[NBUF * BUF_B];   // 131072 B static LDS

    const int tid  = threadIdx.x;
    const int wave = tid >> 6;       // 0..7
    const int lane = tid & 63;
    const int quad = lane >> 4;      // 0..3
    const int l16  = lane & 15;
    const int wm   = wave >> 2;      // 0..1  (M)
    const int wn   = wave & 3;       // 0..3  (N)

    // XCD-chunked swizzle (bijective: 512 wgs, 8 XCDs, 64 wg/chunk)
    int id = blockIdx.y * gridDim.x + blockIdx.x;
    id = (id & 7) * 64 + (id >> 3);
    const int bn = id & 15;          // OUT_F/256 = 16
    const int bm = id >> 4;          // M_TOT/256 = 32

    // ---- staging source coords (per-lane, inverse-swizzled) ----
    // chunk c covers LDS 16B slot c of a 16 KiB half; row r = c>>2,
    // linear col-byte cb' = (c&3)*16, source col cb = cb' ^ swz(r)
    const int c0 = tid, c1 = 512 + tid;
    const int r0 = c0 >> 2, r1 = c1 >> 2;
    const int cb0 = ((c0 & 3) << 4) ^ (((r0 >> 1) & 3) << 4);
    const int cb1 = ((c1 & 3) << 4) ^ (((r1 >> 1) & 3) << 4);
    const ushort* gA0 = A + (size_t)(bm * 256 + r0) * IN_F + (cb0 >> 1);
    const ushort* gA1 = A + (size_t)(bm * 256 + r1) * IN_F + (cb1 >> 1);
    const ushort* gB0 = B + (size_t)(bn * 256 + r0) * IN_F + (cb0 >> 1);
    const ushort* gB1 = B + (size_t)(bn * 256 + r1) * IN_F + (cb1 >> 1);
    // wave-uniform LDS dest bases (HW adds lane*16)
    const int ldsA0 = wave * 1024;
    const int ldsA1 = 8192 + wave * 1024;
    const int ldsB0 = 16384 + wave * 1024;
    const int ldsB1 = 24576 + wave * 1024;

    auto STAGE = [&](int t) {
        char* base = smem + (t & (NBUF - 1)) * BUF_B;
        const int ko = t * BK;
        gl_lds16(gA0 + ko, base + ldsA0);
        gl_lds16(gA1 + ko, base + ldsA1);
        gl_lds16(gB0 + ko, base + ldsB0);
        gl_lds16(gB1 + ko, base + ldsB1);
    };

    // ---- read-side addressing (swizzled) ----
    // swz(row) invariant under row+16 -> compute once per thread
    const int arowb = wm * 128 + l16;
    const int browb = wn * 64 + l16;
    const int aswz = ((arowb >> 1) & 3) << 4;
    const int bswz = ((browb >> 1) & 3) << 4;
    const int acol = (((quad * 16) ^ aswz) >> 1);   // ushort offset in 32-wide row
    const int bcol = (((quad * 16) ^ bswz) >> 1);

    floatx4 acc[8][4] = {};

    auto COMPUTE = [&](int t) {
        const ushort* bufp = (const ushort*)(smem + (t & (NBUF - 1)) * BUF_B);
        bf16x8 af[8], bfr[4];
#pragma unroll
        for (int mi = 0; mi < 8; ++mi)
            af[mi] = *reinterpret_cast<const bf16x8*>(bufp + (arowb + mi * 16) * 32 + acol);
#pragma unroll
        for (int ni = 0; ni < 4; ++ni)
            bfr[ni] = *reinterpret_cast<const bf16x8*>(bufp + 8192 + (browb + ni * 16) * 32 + bcol);
        __builtin_amdgcn_s_setprio(1);
#pragma unroll
        for (int mi = 0; mi < 8; ++mi)
#pragma unroll
            for (int ni = 0; ni < 4; ++ni)
                acc[mi][ni] = __builtin_amdgcn_mfma_f32_16x16x32_bf16(
                    af[mi], bfr[ni], acc[mi][ni], 0, 0, 0);
        __builtin_amdgcn_s_setprio(0);
    };

    // ---- prologue: fill 3 ring slots, drain tile 0 only ----
    STAGE(0); STAGE(1); STAGE(2);
    WAITVM(8);            // 12 issued, drain oldest 4 = tile 0
    FENCE_BARRIER();

    // ---- main loop: one barrier per K-step, 8 loads stay in flight ----
#pragma unroll 1
    for (int t = 0; t < NT - 3; ++t) {   // t = 0..124
        STAGE(t + 3);                    // -> buf[(t+3)&3]; its last reads ended
                                         //    before the previous barrier
        COMPUTE(t);
        WAITVM(8);                       // drain tile t+1; t+2,t+3 stay in flight
        FENCE_BARRIER();
    }
    // ---- tail: drain progressively ----
    COMPUTE(NT - 3); WAITVM(4); FENCE_BARRIER();   // drain tile 126
    COMPUTE(NT - 2); WAITVM(0); FENCE_BARRIER();   // drain tile 127
    COMPUTE(NT - 1);

    // ---- epilogue: D lane map col=l16, row=quad*4+r ----
    const int ccol = bn * 256 + wn * 64 + l16;
    const float* bp = bias + ccol;
    float* Cp = C + (size_t)(bm * 256 + wm * 128 + quad * 4) * OUT_F + ccol;
#pragma unroll
    for (int mi = 0; mi < 8; ++mi) {
#pragma unroll
        for (int ni = 0; ni < 4; ++ni) {
            float bv = bp[ni * 16];
#pragma unroll
            for (int r = 0; r < 4; ++r)
                Cp[(size_t)(mi * 16 + r) * OUT_F + ni * 16] = acc[mi][ni][r] + bv;
        }
    }
}

extern "C" void kernel_launch(void* const* d_in, const int* in_sizes, int n_in,
                              void* d_out, int out_size, void* d_ws, size_t ws_size,
                              hipStream_t stream) {
    const float* x       = (const float*)d_in[0];
    const int*   packed  = (const int*)d_in[1];
    const float* scales  = (const float*)d_in[2];
    const float* offsets = (const float*)d_in[3];
    const float* bias    = (const float*)d_in[4];
    float* out = (float*)d_out;

    ushort* xb = (ushort*)d_ws;                                     // 8192*4096*2 = 64 MiB
    ushort* wb = (ushort*)((char*)d_ws + (size_t)M_TOT * IN_F * 2); // 4096*4096*2 = 32 MiB

    // x: 33,554,432 elems / 8 per thread / 256 per block = 16384 blocks
    cvt_x_kernel<<<16384, 256, 0, stream>>>(x, xb);
    // packed: 8,388,608 elems / 4 per thread / 256 = 8192 blocks
    dequant_kernel<<<8192, 256, 0, stream>>>(packed, scales, offsets, wb);

    dim3 grid(OUT_F / 256, M_TOT / 256);   // (16, 32) = 512 wgs
    gemm_kernel<<<grid, 512, 0, stream>>>(xb, wb, bias, out);
}